// Round 21
// baseline (434.497 us; speedup 1.0000x reference)
//
#include <hip/hip_runtime.h>
#include <cstdint>

// Problem constants
#define NROWS   131072
#define NUNITS  256
#define KTOT    512          // INPUT_DIM + UNITS
#define BM      64           // rows per block
#define THREADS 384          // 6 waves: 4 consumer + 2 producer

typedef float f32x4  __attribute__((ext_vector_type(4)));
typedef short bf16x8 __attribute__((ext_vector_type(8)));

__device__ __forceinline__ short f2bf(float x) {
    unsigned u = __float_as_uint(x);
    u += 0x7FFFu + ((u >> 16) & 1u);   // round-to-nearest-even
    return (short)(u >> 16);
}

// W [512][1024] fp32 -> Wws [16][1024][32] bf16 (B-fragment order, L2-resident).
__global__ void convert_W_kernel(const float* __restrict__ W, short* __restrict__ Wws) {
    int i = blockIdx.x * 256 + threadIdx.x;       // 0 .. 524287
    int k = i >> 10;
    int c = i & 1023;
    Wws[((size_t)(k >> 5) << 15) + ((size_t)c << 5) + (k & 31)] = f2bf(W[i]);
}

// Main: PRODUCER/CONSUMER WAVE SPECIALIZATION (R20 + explicit order-robust
// counted vmcnt -- R20's race was relying on intra-iteration VMEM issue order).
// Grid 8192 = 2048 row-tiles x 4 u-tiles (bijective XCD swizzle).
// Waves 0-3 (consumers): per phase ONLY 8 ds_read_b128 + 16 MFMA + barrier.
// Waves 4-5 (producers): per iteration issue EXACTLY 12 VMEM (8 B gload_lds +
// 4 A dwordx4), then writeA(p+1) (cvt+ds_write), then s_waitcnt vmcnt(12):
// with 24 outstanding this retires the OLDEST 12 = all of (p+1)'s loads
// regardless of intra-iteration issue order. Prologue drains vmcnt(0) once;
// tail vmcnt(0). lgkmcnt(0)+s_barrier publishes A writes.
// Triple-buffered LDS: A 3x4KB + B 3x16KB = 60KB -> 2 blocks/CU, 12 waves/CU.
// Buffer hazards: buf q%3 written during window q-1, read in window q,
// rewritten during window q+2 -> one-window gap. Barriers: 16 == 16.
__global__ void __launch_bounds__(THREADS, 3)
lstm_main_kernel(const float* __restrict__ x, const float* __restrict__ h_prev,
                 const float* __restrict__ c_prev, const float* __restrict__ bias,
                 const float* __restrict__ pi, const float* __restrict__ pf,
                 const float* __restrict__ po, const short* __restrict__ Wws,
                 float* __restrict__ out) {
    __shared__ short Ab[3][2048];   // 3 x 4 KB  bf16 A tiles [64r][32k] swizzled
    __shared__ short Bb[3][8192];   // 3 x 16 KB bf16 B tiles

    const int bid = blockIdx.x;
    const int swz = (bid & 7) * 1024 + (bid >> 3);   // bijective, 8192 % 8 == 0
    const int ut  = swz & 3;
    const int rt  = swz >> 2;
    const int row0 = rt * BM;

    const int t    = threadIdx.x;
    const int lane = t & 63;
    const int w    = t >> 6;             // 0-3 consumer, 4-5 producer

    if (w >= 4) {
        // ======================= PRODUCER (2 waves) =======================
        const int pw = w - 4;            // 0..1
        int a_src[2], a_wr[2];
        #pragma unroll
        for (int j = 0; j < 2; ++j) {
            const int G = pw * 128 + j * 64 + lane;
            const int r = G >> 2, s = G & 3;
            a_src[j] = (row0 + r) * 1024 + s * 32;            // bytes into x/h
            a_wr[j]  = r * 32 + ((s ^ ((r >> 1) & 3)) * 8);   // shorts
        }
        const short* b_src[8];
        #pragma unroll
        for (int j = 0; j < 8; ++j) {
            const int G = pw * 512 + j * 64 + lane;
            const int col = G >> 2, slot = G & 3;
            const int gate = col >> 6, u64c = col & 63;
            b_src[j] = Wws + (size_t)(gate * 256 + ut * 64 + u64c) * 32
                           + ((slot ^ ((col >> 1) & 3)) * 8);
        }

        f32x4 sreg[2][2][2];             // [parity][granule][half]
        auto issueA = [&](int p) {
            const char* base = (const char*)(p < 8 ? x : h_prev) + ((p & 7) << 7);
            #pragma unroll
            for (int j = 0; j < 2; ++j) {
                sreg[p & 1][j][0] = *(const f32x4*)(base + a_src[j]);
                sreg[p & 1][j][1] = *(const f32x4*)(base + a_src[j] + 16);
            }
        };
        auto issueB = [&](int p, int buf) {
            #pragma unroll
            for (int j = 0; j < 8; ++j) {
                __builtin_amdgcn_global_load_lds(
                    (const __attribute__((address_space(1))) uint32_t*)(const void*)
                        (b_src[j] + ((size_t)p << 15)),
                    (__attribute__((address_space(3))) uint32_t*)(void*)
                        (&Bb[buf][(pw * 512 + j * 64) * 8]), 16, 0, 0);
            }
        };
        auto writeA = [&](int p, int buf) {
            #pragma unroll
            for (int j = 0; j < 2; ++j) {
                const f32x4* s = sreg[p & 1][j];
                unsigned v0, v1, v2, v3;
                asm("v_cvt_pk_bf16_f32 %0, %1, %2" : "=v"(v0) : "v"(s[0][0]), "v"(s[0][1]));
                asm("v_cvt_pk_bf16_f32 %0, %1, %2" : "=v"(v1) : "v"(s[0][2]), "v"(s[0][3]));
                asm("v_cvt_pk_bf16_f32 %0, %1, %2" : "=v"(v2) : "v"(s[1][0]), "v"(s[1][1]));
                asm("v_cvt_pk_bf16_f32 %0, %1, %2" : "=v"(v3) : "v"(s[1][2]), "v"(s[1][3]));
                *(int4*)&Ab[buf][a_wr[j]] = make_int4((int)v0, (int)v1, (int)v2, (int)v3);
            }
        };

        // prologue: issue (0) and (1); publish A(0); DRAIN ALL VMEM (startup-
        // only cost; makes the loop invariant order-robust). Bb[0],Bb[1] landed.
        issueB(0, 0); issueA(0);
        issueB(1, 1); issueA(1);
        writeA(0, 0);
        asm volatile("s_waitcnt vmcnt(0) lgkmcnt(0)" ::: "memory");
        __builtin_amdgcn_s_barrier();

        #pragma unroll
        for (int p = 0; p < 15; ++p) {
            if (p <= 13) { issueB(p + 2, (p + 2) % 3); issueA(p + 2); }  // 12 VMEM
            writeA(p + 1, (p + 1) % 3);
            if (p <= 13) {
                // outstanding <= 24 (iters p-1,p); retire oldest 12 = all (p+1)
                asm volatile("s_waitcnt vmcnt(12) lgkmcnt(0)" ::: "memory");
            } else {
                asm volatile("s_waitcnt vmcnt(0) lgkmcnt(0)" ::: "memory");
            }
            __builtin_amdgcn_s_barrier();
        }
        // producers exit; no epilogue
    } else {
        // ======================= CONSUMER (4 waves) =======================
        const int q  = w;                // col quarter 0..3
        const int lr = lane & 15;
        const int hi = lane >> 4;
        const int sw   = (hi ^ ((lr >> 1) & 3)) * 8;
        const int aoff = lr * 32 + sw;                 // + m*512
        const int boff = (q * 16 + lr) * 32 + sw;      // + g*2048

        f32x4 acc[4][4];
        #pragma unroll
        for (int m = 0; m < 4; ++m)
            #pragma unroll
            for (int g = 0; g < 4; ++g)
                acc[m][g] = (f32x4){0.f, 0.f, 0.f, 0.f};

        __builtin_amdgcn_s_barrier();        // matches producer prologue barrier
        asm volatile("" ::: "memory");

        #pragma unroll
        for (int p = 0; p < 16; ++p) {
            const short* A = &Ab[p % 3][0];
            const short* B = &Bb[p % 3][0];
            bf16x8 af[4], bfr[4];
            #pragma unroll
            for (int m = 0; m < 4; ++m)
                af[m] = *(const bf16x8*)&A[aoff + m * 512];
            #pragma unroll
            for (int g = 0; g < 4; ++g)
                bfr[g] = *(const bf16x8*)&B[boff + g * 2048];
            __builtin_amdgcn_s_setprio(1);
            #pragma unroll
            for (int g = 0; g < 4; ++g)
                #pragma unroll
                for (int m = 0; m < 4; ++m)
                    acc[m][g] = __builtin_amdgcn_mfma_f32_16x16x32_bf16(af[m], bfr[g], acc[m][g], 0, 0, 0);
            __builtin_amdgcn_s_setprio(0);
            if (p < 15) {
                asm volatile("" ::: "memory");
                __builtin_amdgcn_s_barrier();
                asm volatile("" ::: "memory");
            }
        }

        // ---- fused LSTM epilogue (lane-local: all 4 gates in acc[m][0..3]) ----
        const size_t HS = (size_t)NROWS * NUNITS;
        const int u = ut * 64 + q * 16 + lr;
        const float bi = bias[u],       bfg = bias[256 + u];
        const float bc = bias[512 + u], bo  = bias[768 + u];
        const float ppi = pi[u], ppf = pf[u], ppo = po[u];
        #pragma unroll
        for (int m = 0; m < 4; ++m) {
            #pragma unroll
            for (int r = 0; r < 4; ++r) {
                const int row = row0 + m * 16 + hi * 4 + r;
                const size_t o = (size_t)row * NUNITS + u;
                const float cp = c_prev[o];
                float zi = acc[m][0][r] + bi  + ppi * cp;
                float zf = acc[m][1][r] + bfg + ppf * cp;
                float zc = acc[m][2][r] + bc;
                float zo = acc[m][3][r] + bo  + ppo * cp;
                float ig = 1.f / (1.f + __expf(-zi));
                float fg = 1.f / (1.f + __expf(-zf));
                float og = 1.f / (1.f + __expf(-zo));
                zc = fminf(fmaxf(zc, -30.f), 30.f);
                float e2 = __expf(2.f * zc);
                float chat = (e2 - 1.f) / (e2 + 1.f);
                float c  = fg * cp + ig * chat;
                float ccl = fminf(fmaxf(c, -30.f), 30.f);
                float e3 = __expf(2.f * ccl);
                float th = (e3 - 1.f) / (e3 + 1.f);
                float h  = og * th;
                out[o]          = h;
                out[HS + o]     = h;
                out[2 * HS + o] = c;
            }
        }
    }
}

extern "C" void kernel_launch(void* const* d_in, const int* in_sizes, int n_in,
                              void* d_out, int out_size, void* d_ws, size_t ws_size,
                              hipStream_t stream) {
    const float* x  = (const float*)d_in[0];
    const float* h  = (const float*)d_in[1];
    const float* c  = (const float*)d_in[2];
    const float* W  = (const float*)d_in[3];
    const float* b  = (const float*)d_in[4];
    const float* pi = (const float*)d_in[5];
    const float* pf = (const float*)d_in[6];
    const float* po = (const float*)d_in[7];
    float* out = (float*)d_out;

    short* Wws = (short*)d_ws;            // 1 MiB bf16 copy of W in B-frag order

    hipLaunchKernelGGL(convert_W_kernel, dim3(2048), dim3(256), 0, stream, W, Wws);
    hipLaunchKernelGGL(lstm_main_kernel, dim3(NROWS / BM * 4), dim3(THREADS), 0, stream,
                       x, h, c, b, pi, pf, po, Wws, out);
}

// Round 22
// 321.494 us; speedup vs baseline: 1.3515x; 1.3515x over previous
//
#include <hip/hip_runtime.h>
#include <cstdint>

// Problem constants
#define NROWS   131072
#define NUNITS  256
#define KTOT    512          // INPUT_DIM + UNITS
#define BM      128          // rows per block
#define THREADS 512

typedef float f32x4  __attribute__((ext_vector_type(4)));
typedef short bf16x8 __attribute__((ext_vector_type(8)));

__device__ __forceinline__ short f2bf(float x) {
    unsigned u = __float_as_uint(x);
    u += 0x7FFFu + ((u >> 16) & 1u);   // round-to-nearest-even
    return (short)(u >> 16);
}

// W [512][1024] fp32 -> Wws [16][1024][32] bf16 (B-fragment order, L2-resident).
__global__ void convert_W_kernel(const float* __restrict__ W, short* __restrict__ Wws) {
    int i = blockIdx.x * 256 + threadIdx.x;       // 0 .. 524287
    int k = i >> 10;
    int c = i & 1023;
    Wws[((size_t)(k >> 5) << 15) + ((size_t)c << 5) + (k & 31)] = f2bf(W[i]);
}

// Main: R19/R12 structure (measured best: 298.6 us total), minus s_setprio
// (T5 is null-to-negative in barrier-lockstep GEMM schedules -- m190).
// grid 4096 = 1024 row-tiles x 4 u-tiles (XCD-swizzled: the 4 u-tiles of a
// row panel co-locate on one XCD -> fp32 A panel HBM-fetched once, L2-served).
// Block: 128 rows x 64 u x 4 gates. 8 waves = 2 row-halves x 4 col-quarters;
// wave tile 64x64, acc[4][4] (all 4 gates lane-local -> fused epilogue).
// NOTE: acc = 64 AGPR + 64 VGPR = 128 regs/wave (unified file) -> 4 waves/SIMD
// hard occupancy ceiling; this is the structural limit of this decomposition.
// Phase p (fully unrolled, 16 phases of BK=32):
//   dmaB(p+1) [2 gload_lds] -> glbA(p+2) [2 dwordx4 fp32] ->
//   writeA(p+1) [auto vmcnt<=4; 4 cvt_pk + ds_write_b128, BEFORE compute] ->
//   compute(p) [8 ds_read_b128 + 16 MFMA] ->
//   s_waitcnt vmcnt(2) lgkmcnt(0)  [retire B(p+1); glbA(p+2) stays in flight]
//   s_barrier
// Epilogue: c_prev loaded inline; plain stores (L2-merged -- R17/R18 showed
// nt stores / burst prefetch double WRITE_SIZE).
// Layouts: verified conflict-free (64B row stride, granule XOR (row>>1)&3;
// B swizzle on gload_lds SOURCE (rule #21), A on the per-lane ds_write).
__global__ void __launch_bounds__(THREADS, 4)
lstm_main_kernel(const float* __restrict__ x, const float* __restrict__ h_prev,
                 const float* __restrict__ c_prev, const float* __restrict__ bias,
                 const float* __restrict__ pi, const float* __restrict__ pf,
                 const float* __restrict__ po, const short* __restrict__ Wws,
                 float* __restrict__ out) {
    __shared__ short Ab[2][4096];   // 2 x 8 KB  bf16 A tiles [128r][32k] swizzled
    __shared__ short Bb[2][8192];   // 2 x 16 KB bf16 B tiles

    const int bid = blockIdx.x;
    const int swz = (bid & 7) * 512 + (bid >> 3);
    const int ut  = swz & 3;
    const int rt  = swz >> 2;
    const int row0 = rt * BM;

    const int t    = threadIdx.x;
    const int lane = t & 63;
    const int w    = t >> 6;
    const int lr   = lane & 15;
    const int hi   = lane >> 4;          // k-granule 0..3
    const int rh   = w >> 2;             // row half 0..1
    const int q    = w & 3;              // col quarter 0..3

    // ---- A staging: thread t -> row t>>2, source granule g = t&3 (8 fp32) ----
    const int arow = t >> 2, ag = t & 3;
    const int avoff = ((row0 + arow) * 256 + ag * 8) * 4;          // bytes into x/h
    const int awr   = arow * 32 + ((ag ^ ((arow >> 1) & 3)) * 8);  // LDS shorts

    // ---- B DMA source byte-offsets (R7 scheme, 0 conflicts measured) ----
    const int u0  = (t >> 2) & 63;
    const int bg0 = t >> 8;              // 0..1
    const int bsw = ((t & 3) ^ ((t >> 3) & 3)) * 8;
    const int bvoff0 = (((bg0    ) * 256 + ut * 64 + u0) * 32 + bsw) * 2;
    const int bvoff1 = (((bg0 + 2) * 256 + ut * 64 + u0) * 32 + bsw) * 2;

    // ---- fragment read offsets (shorts): swizzle matches write side ----
    const int sw   = (hi ^ ((lr >> 1) & 3)) * 8;
    const int aoff = (rh * 64 + lr) * 32 + sw;           // + m*512
    const int boff = (q * 16 + lr) * 32 + sw;            // + g*2048

    f32x4 acc[4][4];
    #pragma unroll
    for (int m = 0; m < 4; ++m)
        #pragma unroll
        for (int g = 0; g < 4; ++g)
            acc[m][g] = (f32x4){0.f, 0.f, 0.f, 0.f};

    f32x4 sreg[2][2];                    // two in-flight A register sets (parity)
    auto glbA = [&](int p) {
        const char* base = (const char*)(p < 8 ? x : h_prev) + ((p & 7) << 7);
        sreg[p & 1][0] = *(const f32x4*)(base + avoff);
        sreg[p & 1][1] = *(const f32x4*)(base + avoff + 16);
    };
    auto writeA = [&](int p) {
        const f32x4* s = sreg[p & 1];
        unsigned u0_, u1_, u2_, u3_;
        asm("v_cvt_pk_bf16_f32 %0, %1, %2" : "=v"(u0_) : "v"(s[0][0]), "v"(s[0][1]));
        asm("v_cvt_pk_bf16_f32 %0, %1, %2" : "=v"(u1_) : "v"(s[0][2]), "v"(s[0][3]));
        asm("v_cvt_pk_bf16_f32 %0, %1, %2" : "=v"(u2_) : "v"(s[1][0]), "v"(s[1][1]));
        asm("v_cvt_pk_bf16_f32 %0, %1, %2" : "=v"(u3_) : "v"(s[1][2]), "v"(s[1][3]));
        int4 v = make_int4((int)u0_, (int)u1_, (int)u2_, (int)u3_);
        *(int4*)&Ab[p & 1][awr] = v;
    };
    auto dmaB = [&](int p) {
        const char* wb = (const char*)Wws + ((size_t)p << 16);
        short* dst = &Bb[p & 1][0];
        __builtin_amdgcn_global_load_lds(
            (const __attribute__((address_space(1))) uint32_t*)(const void*)(wb + bvoff0),
            (__attribute__((address_space(3))) uint32_t*)(void*)(dst + t * 8), 16, 0, 0);
        __builtin_amdgcn_global_load_lds(
            (const __attribute__((address_space(1))) uint32_t*)(const void*)(wb + bvoff1),
            (__attribute__((address_space(3))) uint32_t*)(void*)(dst + 4096 + t * 8), 16, 0, 0);
    };
    auto compute = [&](int p) {
        const short* A = &Ab[p & 1][0];
        const short* B = &Bb[p & 1][0];
        bf16x8 af[4], bfr[4];
        #pragma unroll
        for (int m = 0; m < 4; ++m)
            af[m] = *(const bf16x8*)&A[aoff + m * 512];
        #pragma unroll
        for (int g = 0; g < 4; ++g)
            bfr[g] = *(const bf16x8*)&B[boff + g * 2048];
        #pragma unroll
        for (int g = 0; g < 4; ++g)
            #pragma unroll
            for (int m = 0; m < 4; ++m)
                acc[m][g] = __builtin_amdgcn_mfma_f32_16x16x32_bf16(af[m], bfr[g], acc[m][g], 0, 0, 0);
    };

    // ---- prologue: A(0) published; B(0) done; glbA(1) in flight ----
    glbA(0);
    dmaB(0);
    glbA(1);
    writeA(0);                            // auto-wait retires glbA(0)
    asm volatile("s_waitcnt vmcnt(2) lgkmcnt(0)" ::: "memory");  // B(0) done; glbA(1) in flight
    __builtin_amdgcn_s_barrier();

    #pragma unroll
    for (int p = 0; p < 16; ++p) {
        if (p <= 14) dmaB(p + 1);         // B lookahead 1 (L2-resident, cheap)
        if (p <= 13) glbA(p + 2);         // A lookahead 2 (HBM ~900cyc covered)
        if (p <= 14) writeA(p + 1);       // auto vmcnt<=4: B(p+1), glbA(p+2) stay in flight
        compute(p);
        if (p <= 13) {
            asm volatile("s_waitcnt vmcnt(2) lgkmcnt(0)" ::: "memory");  // retire B(p+1)
            __builtin_amdgcn_s_barrier();
        } else if (p == 14) {
            asm volatile("s_waitcnt vmcnt(0) lgkmcnt(0)" ::: "memory");
            __builtin_amdgcn_s_barrier();
        }
    }

    // ---- fused LSTM epilogue (lane-local: all 4 gates in acc[m][0..3]) ----
    const size_t HS = (size_t)NROWS * NUNITS;
    const int u = ut * 64 + q * 16 + lr;
    const float bi = bias[u],       bfg = bias[256 + u];
    const float bc = bias[512 + u], bo  = bias[768 + u];
    const float ppi = pi[u], ppf = pf[u], ppo = po[u];
    #pragma unroll
    for (int m = 0; m < 4; ++m) {
        #pragma unroll
        for (int r = 0; r < 4; ++r) {
            const int row = row0 + rh * 64 + m * 16 + hi * 4 + r;
            const size_t o = (size_t)row * NUNITS + u;
            const float cp = c_prev[o];
            float zi = acc[m][0][r] + bi  + ppi * cp;
            float zf = acc[m][1][r] + bfg + ppf * cp;
            float zc = acc[m][2][r] + bc;
            float zo = acc[m][3][r] + bo  + ppo * cp;
            float ig = 1.f / (1.f + __expf(-zi));
            float fg = 1.f / (1.f + __expf(-zf));
            float og = 1.f / (1.f + __expf(-zo));
            zc = fminf(fmaxf(zc, -30.f), 30.f);
            float e2 = __expf(2.f * zc);
            float chat = (e2 - 1.f) / (e2 + 1.f);
            float c  = fg * cp + ig * chat;
            float ccl = fminf(fmaxf(c, -30.f), 30.f);
            float e3 = __expf(2.f * ccl);
            float th = (e3 - 1.f) / (e3 + 1.f);
            float h  = og * th;
            out[o]          = h;
            out[HS + o]     = h;
            out[2 * HS + o] = c;
        }
    }
}

extern "C" void kernel_launch(void* const* d_in, const int* in_sizes, int n_in,
                              void* d_out, int out_size, void* d_ws, size_t ws_size,
                              hipStream_t stream) {
    const float* x  = (const float*)d_in[0];
    const float* h  = (const float*)d_in[1];
    const float* c  = (const float*)d_in[2];
    const float* W  = (const float*)d_in[3];
    const float* b  = (const float*)d_in[4];
    const float* pi = (const float*)d_in[5];
    const float* pf = (const float*)d_in[6];
    const float* po = (const float*)d_in[7];
    float* out = (float*)d_out;

    short* Wws = (short*)d_ws;            // 1 MiB bf16 copy of W in B-frag order

    hipLaunchKernelGGL(convert_W_kernel, dim3(2048), dim3(256), 0, stream, W, Wws);
    hipLaunchKernelGGL(lstm_main_kernel, dim3(NROWS / BM * 4), dim3(THREADS), 0, stream,
                       x, h, c, b, pi, pf, po, Wws, out);
}

// Round 23
// 301.691 us; speedup vs baseline: 1.4402x; 1.0656x over previous
//
#include <hip/hip_runtime.h>
#include <cstdint>

// Problem constants
#define NROWS   131072
#define NUNITS  256
#define KTOT    512          // INPUT_DIM + UNITS
#define BM      128          // rows per block
#define THREADS 512

typedef float f32x4  __attribute__((ext_vector_type(4)));
typedef short bf16x8 __attribute__((ext_vector_type(8)));

__device__ __forceinline__ short f2bf(float x) {
    unsigned u = __float_as_uint(x);
    u += 0x7FFFu + ((u >> 16) & 1u);   // round-to-nearest-even
    return (short)(u >> 16);
}

// W [512][1024] fp32 -> Wws [16][1024][32] bf16 (B-fragment order, L2-resident).
__global__ void convert_W_kernel(const float* __restrict__ W, short* __restrict__ Wws) {
    int i = blockIdx.x * 256 + threadIdx.x;       // 0 .. 524287
    int k = i >> 10;
    int c = i & 1023;
    Wws[((size_t)(k >> 5) << 15) + ((size_t)c << 5) + (k & 31)] = f2bf(W[i]);
}

// Main: CHAMPION CONFIGURATION (R19 byte-identical; 298.6 us total measured).
// 23 configurations measured; this is the optimum. WITH s_setprio (R22 A/B:
// removing it costs ~7% -- our schedule has wave role diversity, so T5 pays).
// grid 4096 = 1024 row-tiles x 4 u-tiles (XCD-swizzled: the 4 u-tiles of a
// row panel co-locate on one XCD -> fp32 A panel HBM-fetched once, L2-served).
// Block: 128 rows x 64 u x 4 gates. 8 waves = 2 row-halves x 4 col-quarters;
// wave tile 64x64, acc[4][4] (all 4 gates lane-local -> fused epilogue).
// Limit note: 64 VGPR + 64 AGPR acc = 128 regs/wave -> 4 waves/SIMD occupancy
// ceiling; the barrier-coupled phase latency chain is the structural residual.
// Phase p (fully unrolled, 16 phases of BK=32):
//   dmaB(p+1) [2 gload_lds] -> glbA(p+2) [2 dwordx4 fp32] ->
//   writeA(p+1) [auto vmcnt<=4; 4 cvt_pk + ds_write_b128, BEFORE compute] ->
//   compute(p) [8 ds_read_b128 + 16 MFMA, setprio] ->
//   s_waitcnt vmcnt(2) lgkmcnt(0)  [retire B(p+1); glbA(p+2) stays in flight]
//   s_barrier
// Epilogue: c_prev inline, plain stores (L2-merged; nt/prefetch variants
// doubled WRITE_SIZE -- R17/R18).
// Layouts: verified conflict-free (64B row stride, granule XOR (row>>1)&3;
// B swizzle on gload_lds SOURCE (rule #21), A on the per-lane ds_write).
__global__ void __launch_bounds__(THREADS, 4)
lstm_main_kernel(const float* __restrict__ x, const float* __restrict__ h_prev,
                 const float* __restrict__ c_prev, const float* __restrict__ bias,
                 const float* __restrict__ pi, const float* __restrict__ pf,
                 const float* __restrict__ po, const short* __restrict__ Wws,
                 float* __restrict__ out) {
    __shared__ short Ab[2][4096];   // 2 x 8 KB  bf16 A tiles [128r][32k] swizzled
    __shared__ short Bb[2][8192];   // 2 x 16 KB bf16 B tiles

    const int bid = blockIdx.x;
    const int swz = (bid & 7) * 512 + (bid >> 3);
    const int ut  = swz & 3;
    const int rt  = swz >> 2;
    const int row0 = rt * BM;

    const int t    = threadIdx.x;
    const int lane = t & 63;
    const int w    = t >> 6;
    const int lr   = lane & 15;
    const int hi   = lane >> 4;          // k-granule 0..3
    const int rh   = w >> 2;             // row half 0..1
    const int q    = w & 3;              // col quarter 0..3

    // ---- A staging: thread t -> row t>>2, source granule g = t&3 (8 fp32) ----
    const int arow = t >> 2, ag = t & 3;
    const int avoff = ((row0 + arow) * 256 + ag * 8) * 4;          // bytes into x/h
    const int awr   = arow * 32 + ((ag ^ ((arow >> 1) & 3)) * 8);  // LDS shorts

    // ---- B DMA source byte-offsets (R7 scheme, 0 conflicts measured) ----
    const int u0  = (t >> 2) & 63;
    const int bg0 = t >> 8;              // 0..1
    const int bsw = ((t & 3) ^ ((t >> 3) & 3)) * 8;
    const int bvoff0 = (((bg0    ) * 256 + ut * 64 + u0) * 32 + bsw) * 2;
    const int bvoff1 = (((bg0 + 2) * 256 + ut * 64 + u0) * 32 + bsw) * 2;

    // ---- fragment read offsets (shorts): swizzle matches write side ----
    const int sw   = (hi ^ ((lr >> 1) & 3)) * 8;
    const int aoff = (rh * 64 + lr) * 32 + sw;           // + m*512
    const int boff = (q * 16 + lr) * 32 + sw;            // + g*2048

    f32x4 acc[4][4];
    #pragma unroll
    for (int m = 0; m < 4; ++m)
        #pragma unroll
        for (int g = 0; g < 4; ++g)
            acc[m][g] = (f32x4){0.f, 0.f, 0.f, 0.f};

    f32x4 sreg[2][2];                    // two in-flight A register sets (parity)
    auto glbA = [&](int p) {
        const char* base = (const char*)(p < 8 ? x : h_prev) + ((p & 7) << 7);
        sreg[p & 1][0] = *(const f32x4*)(base + avoff);
        sreg[p & 1][1] = *(const f32x4*)(base + avoff + 16);
    };
    auto writeA = [&](int p) {
        const f32x4* s = sreg[p & 1];
        unsigned u0_, u1_, u2_, u3_;
        asm("v_cvt_pk_bf16_f32 %0, %1, %2" : "=v"(u0_) : "v"(s[0][0]), "v"(s[0][1]));
        asm("v_cvt_pk_bf16_f32 %0, %1, %2" : "=v"(u1_) : "v"(s[0][2]), "v"(s[0][3]));
        asm("v_cvt_pk_bf16_f32 %0, %1, %2" : "=v"(u2_) : "v"(s[1][0]), "v"(s[1][1]));
        asm("v_cvt_pk_bf16_f32 %0, %1, %2" : "=v"(u3_) : "v"(s[1][2]), "v"(s[1][3]));
        int4 v = make_int4((int)u0_, (int)u1_, (int)u2_, (int)u3_);
        *(int4*)&Ab[p & 1][awr] = v;
    };
    auto dmaB = [&](int p) {
        const char* wb = (const char*)Wws + ((size_t)p << 16);
        short* dst = &Bb[p & 1][0];
        __builtin_amdgcn_global_load_lds(
            (const __attribute__((address_space(1))) uint32_t*)(const void*)(wb + bvoff0),
            (__attribute__((address_space(3))) uint32_t*)(void*)(dst + t * 8), 16, 0, 0);
        __builtin_amdgcn_global_load_lds(
            (const __attribute__((address_space(1))) uint32_t*)(const void*)(wb + bvoff1),
            (__attribute__((address_space(3))) uint32_t*)(void*)(dst + 4096 + t * 8), 16, 0, 0);
    };
    auto compute = [&](int p) {
        const short* A = &Ab[p & 1][0];
        const short* B = &Bb[p & 1][0];
        bf16x8 af[4], bfr[4];
        #pragma unroll
        for (int m = 0; m < 4; ++m)
            af[m] = *(const bf16x8*)&A[aoff + m * 512];
        #pragma unroll
        for (int g = 0; g < 4; ++g)
            bfr[g] = *(const bf16x8*)&B[boff + g * 2048];
        __builtin_amdgcn_s_setprio(1);
        #pragma unroll
        for (int g = 0; g < 4; ++g)
            #pragma unroll
            for (int m = 0; m < 4; ++m)
                acc[m][g] = __builtin_amdgcn_mfma_f32_16x16x32_bf16(af[m], bfr[g], acc[m][g], 0, 0, 0);
        __builtin_amdgcn_s_setprio(0);
    };

    // ---- prologue: A(0) published; B(0) done; glbA(1) in flight ----
    glbA(0);
    dmaB(0);
    glbA(1);
    writeA(0);                            // auto-wait retires glbA(0)
    asm volatile("s_waitcnt vmcnt(2) lgkmcnt(0)" ::: "memory");  // B(0) done; glbA(1) in flight
    __builtin_amdgcn_s_barrier();

    #pragma unroll
    for (int p = 0; p < 16; ++p) {
        if (p <= 14) dmaB(p + 1);         // B lookahead 1 (L2-resident, cheap)
        if (p <= 13) glbA(p + 2);         // A lookahead 2 (HBM ~900cyc covered)
        if (p <= 14) writeA(p + 1);       // auto vmcnt<=4: B(p+1), glbA(p+2) stay in flight
        compute(p);
        if (p <= 13) {
            asm volatile("s_waitcnt vmcnt(2) lgkmcnt(0)" ::: "memory");  // retire B(p+1)
            __builtin_amdgcn_s_barrier();
        } else if (p == 14) {
            asm volatile("s_waitcnt vmcnt(0) lgkmcnt(0)" ::: "memory");
            __builtin_amdgcn_s_barrier();
        }
    }

    // ---- fused LSTM epilogue (lane-local: all 4 gates in acc[m][0..3]) ----
    const size_t HS = (size_t)NROWS * NUNITS;
    const int u = ut * 64 + q * 16 + lr;
    const float bi = bias[u],       bfg = bias[256 + u];
    const float bc = bias[512 + u], bo  = bias[768 + u];
    const float ppi = pi[u], ppf = pf[u], ppo = po[u];
    #pragma unroll
    for (int m = 0; m < 4; ++m) {
        #pragma unroll
        for (int r = 0; r < 4; ++r) {
            const int row = row0 + rh * 64 + m * 16 + hi * 4 + r;
            const size_t o = (size_t)row * NUNITS + u;
            const float cp = c_prev[o];
            float zi = acc[m][0][r] + bi  + ppi * cp;
            float zf = acc[m][1][r] + bfg + ppf * cp;
            float zc = acc[m][2][r] + bc;
            float zo = acc[m][3][r] + bo  + ppo * cp;
            float ig = 1.f / (1.f + __expf(-zi));
            float fg = 1.f / (1.f + __expf(-zf));
            float og = 1.f / (1.f + __expf(-zo));
            zc = fminf(fmaxf(zc, -30.f), 30.f);
            float e2 = __expf(2.f * zc);
            float chat = (e2 - 1.f) / (e2 + 1.f);
            float c  = fg * cp + ig * chat;
            float ccl = fminf(fmaxf(c, -30.f), 30.f);
            float e3 = __expf(2.f * ccl);
            float th = (e3 - 1.f) / (e3 + 1.f);
            float h  = og * th;
            out[o]          = h;
            out[HS + o]     = h;
            out[2 * HS + o] = c;
        }
    }
}

extern "C" void kernel_launch(void* const* d_in, const int* in_sizes, int n_in,
                              void* d_out, int out_size, void* d_ws, size_t ws_size,
                              hipStream_t stream) {
    const float* x  = (const float*)d_in[0];
    const float* h  = (const float*)d_in[1];
    const float* c  = (const float*)d_in[2];
    const float* W  = (const float*)d_in[3];
    const float* b  = (const float*)d_in[4];
    const float* pi = (const float*)d_in[5];
    const float* pf = (const float*)d_in[6];
    const float* po = (const float*)d_in[7];
    float* out = (float*)d_out;

    short* Wws = (short*)d_ws;            // 1 MiB bf16 copy of W in B-frag order

    hipLaunchKernelGGL(convert_W_kernel, dim3(2048), dim3(256), 0, stream, W, Wws);
    hipLaunchKernelGGL(lstm_main_kernel, dim3(NROWS / BM * 4), dim3(THREADS), 0, stream,
                       x, h, c, b, pi, pf, po, Wws, out);
}